// Round 7
// baseline (361.728 us; speedup 1.0000x reference)
//
#include <hip/hip_runtime.h>

#define S 4096
#define DM 1024
#define NH 16
#define HD 64

typedef __attribute__((ext_vector_type(8))) short bf8;
typedef __attribute__((ext_vector_type(4))) float f4;
typedef __attribute__((ext_vector_type(4))) short s4;

#define MFMA __builtin_amdgcn_mfma_f32_16x16x32_bf16

// softmax scale folded into Q, in base-2 domain: 1/sqrt(64) * log2(e)
#define QSCALE 0.18033688011112042f

static __device__ __forceinline__ unsigned short f2b(float f) {
  unsigned int u = __builtin_bit_cast(unsigned int, f);
  u += 0x7fffu + ((u >> 16) & 1u);   // RNE
  return (unsigned short)(u >> 16);
}
static __device__ __forceinline__ float b2f(unsigned short u) {
  return __builtin_bit_cast(float, (unsigned int)u << 16);
}

// async global->LDS, 16B per lane. LDS dest must be WAVE-UNIFORM base;
// HW scatters lane i to base + i*16.
static __device__ __forceinline__ void gld_lds(const unsigned short* g, unsigned short* l) {
  __builtin_amdgcn_global_load_lds(
      (const __attribute__((address_space(1))) unsigned int*)g,
      (__attribute__((address_space(3))) unsigned int*)l, 16, 0, 0);
}

// ------------- fused prep: cast x->bf16 ; transpose+cast w_qkv, w_out -------------
// blocks 0..4095: cast x (4M elems). 4096..4863: wqkvT tiles. 4864..5119: woutT tiles.
__global__ void prep(const float* __restrict__ x, const float* __restrict__ w_qkv,
                     const float* __restrict__ w_out,
                     unsigned short* __restrict__ xb, unsigned short* __restrict__ wqkvT,
                     unsigned short* __restrict__ woutT) {
  __shared__ float tile[64][65];
  int b = blockIdx.x, t = threadIdx.x;
  if (b < 4096) {
    int i = (b * 256 + t) * 4;
    float4 v = *(const float4*)(x + i);
    s4 o;
    o.x = (short)f2b(v.x); o.y = (short)f2b(v.y);
    o.z = (short)f2b(v.z); o.w = (short)f2b(v.w);
    *(s4*)(xb + i) = o;
    return;
  }
  const float* in; unsigned short* out; int R, C, tc, tr;
  if (b < 4096 + 768) { int bb = b - 4096; in = w_qkv; out = wqkvT; R = DM; C = 3 * DM; tc = bb % 48; tr = bb / 48; }
  else                { int bb = b - 4864; in = w_out; out = woutT; R = DM; C = DM;     tc = bb % 16; tr = bb / 16; }
  int c = t & 63, rbase = (t >> 6) * 16;
#pragma unroll
  for (int i = 0; i < 16; i++) {
    int r = rbase + i;
    tile[r][c] = in[(tr * 64 + r) * C + tc * 64 + c];
  }
  __syncthreads();
#pragma unroll
  for (int i = 0; i < 16; i++) {
    int cc = rbase + i;
    out[(tc * 64 + cc) * R + tr * 64 + c] = f2b(tile[c][cc]);
  }
}

// =================================================================
// m97-style 128x128 GEMM core, BK=32, 256 threads (4 waves, 2x2 of 64x64).
// =================================================================

// ------------- QKV GEMM + scatter epilogue -------------
__global__ void __launch_bounds__(256, 2) gemm_qkv(const unsigned short* __restrict__ A,
                                                   const unsigned short* __restrict__ Bt,
                                                   const float* __restrict__ bias,
                                                   unsigned short* __restrict__ Qo,
                                                   unsigned short* __restrict__ Ko,
                                                   unsigned short* __restrict__ Vt) {
  __shared__ unsigned short lA[128 * 32];
  __shared__ unsigned short lB[128 * 32];
  int bid = blockIdx.x;
  int nb = bid % 24, mb = bid / 24;
  int m0 = mb * 128, n0 = nb * 128;
  int t = threadIdx.x, w = t >> 6, lane = t & 63;
  int col = lane & 15, quad = lane >> 4;
  int wm = (w >> 1) * 64, wn = (w & 1) * 64;

  int srow = lane >> 2;          // 0..15 within a 16-row staging group
  int sphys = lane & 3;

  f4 acc[4][4];
#pragma unroll
  for (int x = 0; x < 4; x++)
#pragma unroll
    for (int y = 0; y < 4; y++) acc[x][y] = (f4){0.f, 0.f, 0.f, 0.f};

  for (int k0 = 0; k0 < DM; k0 += 32) {
    __syncthreads();   // WAR: prev-step consumers done
#pragma unroll
    for (int p = 0; p < 2; p++) {
      int j = 2 * w + p;
      int row = j * 16 + srow;                 // 0..127
      int lch = sphys ^ ((srow >> 1) & 3);     // logical 16B chunk to fetch
      gld_lds(A + (size_t)(m0 + row) * DM + k0 + lch * 8, lA + j * 512);
      gld_lds(Bt + (size_t)(n0 + row) * DM + k0 + lch * 8, lB + j * 512);
    }
    __syncthreads();   // staged data visible

    bf8 af[4], bfr[4];
#pragma unroll
    for (int x = 0; x < 4; x++) {
      int rA = wm + x * 16 + col;
      af[x] = *(const bf8*)(lA + rA * 32 + (quad ^ ((col >> 1) & 3)) * 8);
      int rB = wn + x * 16 + col;
      bfr[x] = *(const bf8*)(lB + rB * 32 + (quad ^ ((col >> 1) & 3)) * 8);
    }
#pragma unroll
    for (int x = 0; x < 4; x++)
#pragma unroll
      for (int y = 0; y < 4; y++)
        acc[x][y] = MFMA(af[x], bfr[y], acc[x][y], 0, 0, 0);
  }

  // epilogue: scatter to Q (scaled), K, Vt
#pragma unroll
  for (int x = 0; x < 4; x++) {
    int s0r = m0 + wm + x * 16 + quad * 4;
#pragma unroll
    for (int y = 0; y < 4; y++) {
      f4 a = acc[x][y];
      int n = n0 + wn + y * 16 + col;
      float bv = bias[n];
      if (n < 2048) {
        unsigned short* dst = (n < 1024) ? Qo : Ko;
        float sc = (n < 1024) ? QSCALE : 1.0f;
        int nn = n & 1023;
        int hh = nn >> 6, d = nn & 63;
        unsigned short* pp = dst + ((size_t)hh * S + s0r) * HD + d;
#pragma unroll
        for (int r = 0; r < 4; r++) pp[r * HD] = f2b((a[r] + bv) * sc);
      } else {
        int nn = n - 2048;
        int hh = nn >> 6, d = nn & 63;
        s4 pk;
        pk.x = (short)f2b(a[0] + bv);
        pk.y = (short)f2b(a[1] + bv);
        pk.z = (short)f2b(a[2] + bv);
        pk.w = (short)f2b(a[3] + bv);
        *(s4*)(Vt + ((size_t)hh * HD + d) * S + s0r) = pk;
      }
    }
  }
}

// ------------- Out GEMM: ctx x woutT + bias -> fp32 -------------
__global__ void __launch_bounds__(256, 2) gemm_out(const unsigned short* __restrict__ A,
                                                   const unsigned short* __restrict__ Bt,
                                                   const float* __restrict__ bias,
                                                   float* __restrict__ out) {
  __shared__ unsigned short lA[128 * 32];
  __shared__ unsigned short lB[128 * 32];
  int bid = blockIdx.x;
  int nb = bid % 8, mb = bid / 8;
  int m0 = mb * 128, n0 = nb * 128;
  int t = threadIdx.x, w = t >> 6, lane = t & 63;
  int col = lane & 15, quad = lane >> 4;
  int wm = (w >> 1) * 64, wn = (w & 1) * 64;

  int srow = lane >> 2;
  int sphys = lane & 3;

  f4 acc[4][4];
#pragma unroll
  for (int x = 0; x < 4; x++)
#pragma unroll
    for (int y = 0; y < 4; y++) acc[x][y] = (f4){0.f, 0.f, 0.f, 0.f};

  for (int k0 = 0; k0 < DM; k0 += 32) {
    __syncthreads();
#pragma unroll
    for (int p = 0; p < 2; p++) {
      int j = 2 * w + p;
      int row = j * 16 + srow;
      int lch = sphys ^ ((srow >> 1) & 3);
      gld_lds(A + (size_t)(m0 + row) * DM + k0 + lch * 8, lA + j * 512);
      gld_lds(Bt + (size_t)(n0 + row) * DM + k0 + lch * 8, lB + j * 512);
    }
    __syncthreads();

    bf8 af[4], bfr[4];
#pragma unroll
    for (int x = 0; x < 4; x++) {
      int rA = wm + x * 16 + col;
      af[x] = *(const bf8*)(lA + rA * 32 + (quad ^ ((col >> 1) & 3)) * 8);
      int rB = wn + x * 16 + col;
      bfr[x] = *(const bf8*)(lB + rB * 32 + (quad ^ ((col >> 1) & 3)) * 8);
    }
#pragma unroll
    for (int x = 0; x < 4; x++)
#pragma unroll
      for (int y = 0; y < 4; y++)
        acc[x][y] = MFMA(af[x], bfr[y], acc[x][y], 0, 0, 0);
  }

#pragma unroll
  for (int x = 0; x < 4; x++) {
    int s0r = m0 + wm + x * 16 + quad * 4;
#pragma unroll
    for (int y = 0; y < 4; y++) {
      f4 a = acc[x][y];
      int n = n0 + wn + y * 16 + col;
      float bv = bias[n];
#pragma unroll
      for (int r = 0; r < 4; r++) out[(size_t)(s0r + r) * DM + n] = a[r] + bv;
    }
  }
}

// =================================================================
// Flash attention v5: BARRIER-FREE kv-loop.
// Fixed-max softmax (m=0), 2 q-tiles (32 q-rows) per wave, K and V
// fragments loaded DIRECTLY from global (L2-resident), P round-trips
// per-wave XOR-swizzled LDS (no __syncthreads anywhere in the loop).
// Split-2 schedule per head (48 slots): slots 0..31 = halves of
// g=31..16 (nst=g+1 each), slots 32..47 = singles g=15..0 (nst=2g+2).
// Longest-first. Rows >= 2048: unnormalized bf16 partial -> ctx/slabB
// + lA/lB; rows < 2048: normalized write to ctx. No atomics, no memset.
// =================================================================
__global__ void __launch_bounds__(256, 4) attn(const unsigned short* __restrict__ Q,
                                               const unsigned short* __restrict__ K,
                                               const unsigned short* __restrict__ Vt,
                                               unsigned short* __restrict__ Ctx,
                                               unsigned short* __restrict__ slabB,
                                               float* __restrict__ lA_g,
                                               float* __restrict__ lB_g) {
  __shared__ unsigned short pbuf[4 * 2 * 16 * 64];   // per-wave P, XOR-swizzled, 16 KB

  int bid = blockIdx.x;
  int h = bid & 15, slot = bid >> 4;
  int g, c0, nst, isB;
  if (slot < 32) {
    g = 31 - (slot >> 1);
    nst = g + 1;
    isB = slot & 1;
    c0 = isB ? nst : 0;
  } else {
    g = 47 - slot;
    nst = 2 * g + 2;
    c0 = 0;
    isB = 0;
  }
  bool single = (g < 16);

  int t = threadIdx.x, w = t >> 6, lane = t & 63;
  int col = lane & 15, quad = lane >> 4;
  int q0a = g * 128 + w * 32;
  int q0b = q0a + 16;

  const unsigned short* Qh = Q + (size_t)h * S * HD;
  const unsigned short* Kh = K + (size_t)h * S * HD;
  const unsigned short* Vh = Vt + (size_t)h * HD * S;
  unsigned short* pla = pbuf + w * (2 * 16 * 64);
  unsigned short* plb = pla + 16 * 64;

  // Q^T B-fragments for both q-tiles
  bf8 qa0 = *(const bf8*)(Qh + (q0a + col) * HD + quad * 8);
  bf8 qa1 = *(const bf8*)(Qh + (q0a + col) * HD + 32 + quad * 8);
  bf8 qb0 = *(const bf8*)(Qh + (q0b + col) * HD + quad * 8);
  bf8 qb1 = *(const bf8*)(Qh + (q0b + col) * HD + 32 + quad * 8);

  f4 oa[4], ob[4];
#pragma unroll
  for (int dt = 0; dt < 4; dt++) { oa[dt] = (f4){0.f,0.f,0.f,0.f}; ob[dt] = (f4){0.f,0.f,0.f,0.f}; }
  float lsa = 0.f, lsb = 0.f;

  int cs = col & 7;
  // P LDS addressing (per 16-row tile, row = col, stride 64 shorts = 128B):
  //  write (s4, 8B): chunk = tt*2 + (quad>>1), half = quad&1; phys = chunk ^ cs
  //  read  (b128):   chunk = quad + 4*chn;                    phys = chunk ^ cs
  char* pwa = (char*)pla + col * 128 + ((quad & 1) << 3);
  char* pwb = (char*)plb + col * 128 + ((quad & 1) << 3);

  for (int s_ = 0; s_ < nst; s_++) {
    int kv0 = (c0 + s_) * 64;

    // ---- K fragments direct from global ----
    bf8 kf0[4], kf1[4];
#pragma unroll
    for (int tt = 0; tt < 4; tt++) {
      const unsigned short* kp = Kh + (size_t)(kv0 + tt * 16 + col) * HD + quad * 8;
      kf0[tt] = *(const bf8*)(kp);
      kf1[tt] = *(const bf8*)(kp + 32);
    }
    // ---- V fragments direct from global ----
    bf8 vf0[4], vf1[4];
#pragma unroll
    for (int dt = 0; dt < 4; dt++) {
      const unsigned short* vp = Vh + (size_t)(dt * 16 + col) * S + kv0 + quad * 8;
      vf0[dt] = *(const bf8*)(vp);
      vf1[dt] = *(const bf8*)(vp + 32);
    }

    // ---- scores S^T[kv][q] for both q-tiles ----
    f4 sta[4], stb[4];
#pragma unroll
    for (int tt = 0; tt < 4; tt++) {
      f4 z = {0.f, 0.f, 0.f, 0.f};
      z = MFMA(kf0[tt], qa0, z, 0, 0, 0);
      z = MFMA(kf1[tt], qa1, z, 0, 0, 0);
      sta[tt] = z;
      f4 y = {0.f, 0.f, 0.f, 0.f};
      y = MFMA(kf0[tt], qb0, y, 0, 0, 0);
      y = MFMA(kf1[tt], qb1, y, 0, 0, 0);
      stb[tt] = y;
    }

    if (kv0 + 63 > q0a) {
      int q = q0a + col;
#pragma unroll
      for (int tt = 0; tt < 4; tt++)
#pragma unroll
        for (int rr = 0; rr < 4; rr++) {
          int kv = kv0 + tt * 16 + quad * 4 + rr;
          sta[tt][rr] = (kv <= q) ? sta[tt][rr] : -1e30f;
        }
    }
    if (kv0 + 63 > q0b) {
      int q = q0b + col;
#pragma unroll
      for (int tt = 0; tt < 4; tt++)
#pragma unroll
        for (int rr = 0; rr < 4; rr++) {
          int kv = kv0 + tt * 16 + quad * 4 + rr;
          stb[tt][rr] = (kv <= q) ? stb[tt][rr] : -1e30f;
        }
    }

    // ---- fixed-max softmax: p = exp2(st); per-lane l accumulate ----
#pragma unroll
    for (int tt = 0; tt < 4; tt++) {
      int poff = (((tt * 2 + (quad >> 1)) ^ cs) << 4);
      float a0 = __builtin_amdgcn_exp2f(sta[tt][0]);
      float a1 = __builtin_amdgcn_exp2f(sta[tt][1]);
      float a2 = __builtin_amdgcn_exp2f(sta[tt][2]);
      float a3 = __builtin_amdgcn_exp2f(sta[tt][3]);
      lsa += (a0 + a1) + (a2 + a3);
      s4 pk;
      pk.x = (short)f2b(a0); pk.y = (short)f2b(a1);
      pk.z = (short)f2b(a2); pk.w = (short)f2b(a3);
      *(s4*)(pwa + poff) = pk;

      float b0 = __builtin_amdgcn_exp2f(stb[tt][0]);
      float b1 = __builtin_amdgcn_exp2f(stb[tt][1]);
      float b2 = __builtin_amdgcn_exp2f(stb[tt][2]);
      float b3 = __builtin_amdgcn_exp2f(stb[tt][3]);
      lsb += (b0 + b1) + (b2 + b3);
      s4 qk;
      qk.x = (short)f2b(b0); qk.y = (short)f2b(b1);
      qk.z = (short)f2b(b2); qk.w = (short)f2b(b3);
      *(s4*)(pwb + poff) = qk;
    }

    // ---- P A-fragments (own-wave LDS; same-wave RAW ordered at DS unit) ----
    bf8 pa0 = *(const bf8*)((char*)pla + col * 128 + (((quad + 0) ^ cs) << 4));
    bf8 pa1 = *(const bf8*)((char*)pla + col * 128 + (((quad + 4) ^ cs) << 4));
    bf8 pb0 = *(const bf8*)((char*)plb + col * 128 + (((quad + 0) ^ cs) << 4));
    bf8 pb1 = *(const bf8*)((char*)plb + col * 128 + (((quad + 4) ^ cs) << 4));

#pragma unroll
    for (int dt = 0; dt < 4; dt++) {
      oa[dt] = MFMA(pa0, vf0[dt], oa[dt], 0, 0, 0);
      oa[dt] = MFMA(pa1, vf1[dt], oa[dt], 0, 0, 0);
      ob[dt] = MFMA(pb0, vf0[dt], ob[dt], 0, 0, 0);
      ob[dt] = MFMA(pb1, vf1[dt], ob[dt], 0, 0, 0);
    }
  }

  // ---- epilogue ----
  lsa += __shfl_xor(lsa, 16); lsa += __shfl_xor(lsa, 32);
  lsb += __shfl_xor(lsb, 16); lsb += __shfl_xor(lsb, 32);

  if (single) {
    float ia = 1.0f / lsa, ib = 1.0f / lsb;
    float ira[4], irb[4];
#pragma unroll
    for (int r = 0; r < 4; r++) { ira[r] = __shfl(ia, quad * 4 + r); irb[r] = __shfl(ib, quad * 4 + r); }
#pragma unroll
    for (int dt = 0; dt < 4; dt++)
#pragma unroll
      for (int r = 0; r < 4; r++) {
        Ctx[(size_t)(q0a + quad * 4 + r) * DM + h * HD + dt * 16 + col] = f2b(oa[dt][r] * ira[r]);
        Ctx[(size_t)(q0b + quad * 4 + r) * DM + h * HD + dt * 16 + col] = f2b(ob[dt][r] * irb[r]);
      }
  } else {
    unsigned short* dst = isB ? slabB : Ctx;
    int rb = isB ? 2048 : 0;
    float* lg = isB ? lB_g : lA_g;
    if (quad == 0) {
      lg[h * S + q0a + col] = lsa;
      lg[h * S + q0b + col] = lsb;
    }
#pragma unroll
    for (int dt = 0; dt < 4; dt++)
#pragma unroll
      for (int r = 0; r < 4; r++) {
        dst[(size_t)(q0a + quad * 4 + r - rb) * DM + h * HD + dt * 16 + col] = f2b(oa[dt][r]);
        dst[(size_t)(q0b + quad * 4 + r - rb) * DM + h * HD + dt * 16 + col] = f2b(ob[dt][r]);
      }
  }
}

// ------------- combine bf16 partials -> normalized ctx rows 2048+ -------------
__global__ void combine(unsigned short* __restrict__ Ctx,
                        const unsigned short* __restrict__ slabB,
                        const float* __restrict__ lA_g,
                        const float* __restrict__ lB_g) {
  int row = 2048 + blockIdx.x;
  int cc = threadIdx.x * 4;
  int h = cc >> 6;
  s4 a = *(const s4*)(Ctx + (size_t)row * DM + cc);
  s4 b = *(const s4*)(slabB + (size_t)(row - 2048) * DM + cc);
  float l = lA_g[h * S + row] + lB_g[h * S + row];
  float inv = 1.0f / l;
  s4 o;
  o.x = (short)f2b((b2f((unsigned short)a.x) + b2f((unsigned short)b.x)) * inv);
  o.y = (short)f2b((b2f((unsigned short)a.y) + b2f((unsigned short)b.y)) * inv);
  o.z = (short)f2b((b2f((unsigned short)a.z) + b2f((unsigned short)b.z)) * inv);
  o.w = (short)f2b((b2f((unsigned short)a.w) + b2f((unsigned short)b.w)) * inv);
  *(s4*)(Ctx + (size_t)row * DM + cc) = o;
}

extern "C" void kernel_launch(void* const* d_in, const int* in_sizes, int n_in,
                              void* d_out, int out_size, void* d_ws, size_t ws_size,
                              hipStream_t stream) {
  const float* x     = (const float*)d_in[0];
  const float* w_qkv = (const float*)d_in[1];
  const float* b_qkv = (const float*)d_in[2];
  const float* w_out = (const float*)d_in[3];
  const float* b_out = (const float*)d_in[4];
  float* out = (float*)d_out;

  char* ws = (char*)d_ws;
  unsigned short* xb    = (unsigned short*)(ws);                        //  8 MB (dead after gemm_qkv)
  unsigned short* wqkvT = (unsigned short*)(ws + (size_t)8  * 1048576); //  6 MB (dead after gemm_qkv)
  unsigned short* woutT = (unsigned short*)(ws + (size_t)14 * 1048576); //  2 MB (live till gemm_out)
  unsigned short* Qb    = (unsigned short*)(ws + (size_t)16 * 1048576); //  8 MB
  unsigned short* Kb    = (unsigned short*)(ws + (size_t)24 * 1048576); //  8 MB
  unsigned short* Vtb   = (unsigned short*)(ws + (size_t)32 * 1048576); //  8 MB
  unsigned short* ctx   = (unsigned short*)(ws + (size_t)40 * 1048576); //  8 MB

  // dead-region reuse after gemm_qkv:
  unsigned short* slabB = xb;                                           // 4 MB (rows 2048+)
  float* lA_g = (float*)wqkvT;                                          // 256 KB
  float* lB_g = (float*)(ws + (size_t)8 * 1048576 + 512 * 1024);        // 256 KB

  prep<<<5120, 256, 0, stream>>>(x, w_qkv, w_out, xb, wqkvT, woutT);
  gemm_qkv<<<32 * 24, 256, 0, stream>>>(xb, wqkvT, b_qkv, Qb, Kb, Vtb);
  attn<<<NH * 48, 256, 0, stream>>>(Qb, Kb, Vtb, ctx, slabB, lA_g, lB_g);
  combine<<<2048, 256, 0, stream>>>(ctx, slabB, lA_g, lB_g);
  gemm_out<<<32 * 8, 256, 0, stream>>>(ctx, woutT, b_out, out);
}

// Round 8
// 212.655 us; speedup vs baseline: 1.7010x; 1.7010x over previous
//
#include <hip/hip_runtime.h>

#define S 4096
#define DM 1024
#define NH 16
#define HD 64

typedef __attribute__((ext_vector_type(8))) short bf8;
typedef __attribute__((ext_vector_type(4))) float f4;
typedef __attribute__((ext_vector_type(4))) short s4;

#define MFMA __builtin_amdgcn_mfma_f32_16x16x32_bf16

// softmax scale folded into Q, in base-2 domain: 1/sqrt(64) * log2(e)
#define QSCALE 0.18033688011112042f

static __device__ __forceinline__ unsigned short f2b(float f) {
  unsigned int u = __builtin_bit_cast(unsigned int, f);
  u += 0x7fffu + ((u >> 16) & 1u);   // RNE
  return (unsigned short)(u >> 16);
}
static __device__ __forceinline__ float b2f(unsigned short u) {
  return __builtin_bit_cast(float, (unsigned int)u << 16);
}

// async global->LDS, 16B per lane. LDS dest must be WAVE-UNIFORM base;
// HW scatters lane i to base + i*16.
static __device__ __forceinline__ void gld_lds(const unsigned short* g, unsigned short* l) {
  __builtin_amdgcn_global_load_lds(
      (const __attribute__((address_space(1))) unsigned int*)g,
      (__attribute__((address_space(3))) unsigned int*)l, 16, 0, 0);
}

// ------------- fused prep: cast x->bf16 ; transpose+cast w_qkv, w_out -------------
// blocks 0..4095: cast x (4M elems). 4096..4863: wqkvT tiles. 4864..5119: woutT tiles.
__global__ void prep(const float* __restrict__ x, const float* __restrict__ w_qkv,
                     const float* __restrict__ w_out,
                     unsigned short* __restrict__ xb, unsigned short* __restrict__ wqkvT,
                     unsigned short* __restrict__ woutT) {
  __shared__ float tile[64][65];
  int b = blockIdx.x, t = threadIdx.x;
  if (b < 4096) {
    int i = (b * 256 + t) * 4;
    float4 v = *(const float4*)(x + i);
    s4 o;
    o.x = (short)f2b(v.x); o.y = (short)f2b(v.y);
    o.z = (short)f2b(v.z); o.w = (short)f2b(v.w);
    *(s4*)(xb + i) = o;
    return;
  }
  const float* in; unsigned short* out; int R, C, tc, tr;
  if (b < 4096 + 768) { int bb = b - 4096; in = w_qkv; out = wqkvT; R = DM; C = 3 * DM; tc = bb % 48; tr = bb / 48; }
  else                { int bb = b - 4864; in = w_out; out = woutT; R = DM; C = DM;     tc = bb % 16; tr = bb / 16; }
  int c = t & 63, rbase = (t >> 6) * 16;
#pragma unroll
  for (int i = 0; i < 16; i++) {
    int r = rbase + i;
    tile[r][c] = in[(tr * 64 + r) * C + tc * 64 + c];
  }
  __syncthreads();
#pragma unroll
  for (int i = 0; i < 16; i++) {
    int cc = rbase + i;
    out[(tc * 64 + cc) * R + tr * 64 + c] = f2b(tile[c][cc]);
  }
}

// =================================================================
// m97-style 128x128 GEMM core, BK=32, 256 threads (4 waves, 2x2 of 64x64).
// =================================================================

// ------------- QKV GEMM + scatter epilogue -------------
__global__ void __launch_bounds__(256, 2) gemm_qkv(const unsigned short* __restrict__ A,
                                                   const unsigned short* __restrict__ Bt,
                                                   const float* __restrict__ bias,
                                                   unsigned short* __restrict__ Qo,
                                                   unsigned short* __restrict__ Ko,
                                                   unsigned short* __restrict__ Vt) {
  __shared__ unsigned short lA[128 * 32];
  __shared__ unsigned short lB[128 * 32];
  int bid = blockIdx.x;
  int nb = bid % 24, mb = bid / 24;
  int m0 = mb * 128, n0 = nb * 128;
  int t = threadIdx.x, w = t >> 6, lane = t & 63;
  int col = lane & 15, quad = lane >> 4;
  int wm = (w >> 1) * 64, wn = (w & 1) * 64;

  int srow = lane >> 2;          // 0..15 within a 16-row staging group
  int sphys = lane & 3;

  f4 acc[4][4];
#pragma unroll
  for (int x = 0; x < 4; x++)
#pragma unroll
    for (int y = 0; y < 4; y++) acc[x][y] = (f4){0.f, 0.f, 0.f, 0.f};

  for (int k0 = 0; k0 < DM; k0 += 32) {
    __syncthreads();   // WAR: prev-step consumers done
#pragma unroll
    for (int p = 0; p < 2; p++) {
      int j = 2 * w + p;
      int row = j * 16 + srow;                 // 0..127
      int lch = sphys ^ ((srow >> 1) & 3);     // logical 16B chunk to fetch
      gld_lds(A + (size_t)(m0 + row) * DM + k0 + lch * 8, lA + j * 512);
      gld_lds(Bt + (size_t)(n0 + row) * DM + k0 + lch * 8, lB + j * 512);
    }
    __syncthreads();   // staged data visible

    bf8 af[4], bfr[4];
#pragma unroll
    for (int x = 0; x < 4; x++) {
      int rA = wm + x * 16 + col;
      af[x] = *(const bf8*)(lA + rA * 32 + (quad ^ ((col >> 1) & 3)) * 8);
      int rB = wn + x * 16 + col;
      bfr[x] = *(const bf8*)(lB + rB * 32 + (quad ^ ((col >> 1) & 3)) * 8);
    }
#pragma unroll
    for (int x = 0; x < 4; x++)
#pragma unroll
      for (int y = 0; y < 4; y++)
        acc[x][y] = MFMA(af[x], bfr[y], acc[x][y], 0, 0, 0);
  }

  // epilogue: scatter to Q (scaled), K, Vt
#pragma unroll
  for (int x = 0; x < 4; x++) {
    int s0r = m0 + wm + x * 16 + quad * 4;
#pragma unroll
    for (int y = 0; y < 4; y++) {
      f4 a = acc[x][y];
      int n = n0 + wn + y * 16 + col;
      float bv = bias[n];
      if (n < 2048) {
        unsigned short* dst = (n < 1024) ? Qo : Ko;
        float sc = (n < 1024) ? QSCALE : 1.0f;
        int nn = n & 1023;
        int hh = nn >> 6, d = nn & 63;
        unsigned short* pp = dst + ((size_t)hh * S + s0r) * HD + d;
#pragma unroll
        for (int r = 0; r < 4; r++) pp[r * HD] = f2b((a[r] + bv) * sc);
      } else {
        int nn = n - 2048;
        int hh = nn >> 6, d = nn & 63;
        s4 pk;
        pk.x = (short)f2b(a[0] + bv);
        pk.y = (short)f2b(a[1] + bv);
        pk.z = (short)f2b(a[2] + bv);
        pk.w = (short)f2b(a[3] + bv);
        *(s4*)(Vt + ((size_t)hh * HD + d) * S + s0r) = pk;
      }
    }
  }
}

// ------------- Out GEMM: ctx x woutT + bias -> fp32 -------------
__global__ void __launch_bounds__(256, 2) gemm_out(const unsigned short* __restrict__ A,
                                                   const unsigned short* __restrict__ Bt,
                                                   const float* __restrict__ bias,
                                                   float* __restrict__ out) {
  __shared__ unsigned short lA[128 * 32];
  __shared__ unsigned short lB[128 * 32];
  int bid = blockIdx.x;
  int nb = bid % 8, mb = bid / 8;
  int m0 = mb * 128, n0 = nb * 128;
  int t = threadIdx.x, w = t >> 6, lane = t & 63;
  int col = lane & 15, quad = lane >> 4;
  int wm = (w >> 1) * 64, wn = (w & 1) * 64;

  int srow = lane >> 2;
  int sphys = lane & 3;

  f4 acc[4][4];
#pragma unroll
  for (int x = 0; x < 4; x++)
#pragma unroll
    for (int y = 0; y < 4; y++) acc[x][y] = (f4){0.f, 0.f, 0.f, 0.f};

  for (int k0 = 0; k0 < DM; k0 += 32) {
    __syncthreads();
#pragma unroll
    for (int p = 0; p < 2; p++) {
      int j = 2 * w + p;
      int row = j * 16 + srow;
      int lch = sphys ^ ((srow >> 1) & 3);
      gld_lds(A + (size_t)(m0 + row) * DM + k0 + lch * 8, lA + j * 512);
      gld_lds(Bt + (size_t)(n0 + row) * DM + k0 + lch * 8, lB + j * 512);
    }
    __syncthreads();

    bf8 af[4], bfr[4];
#pragma unroll
    for (int x = 0; x < 4; x++) {
      int rA = wm + x * 16 + col;
      af[x] = *(const bf8*)(lA + rA * 32 + (quad ^ ((col >> 1) & 3)) * 8);
      int rB = wn + x * 16 + col;
      bfr[x] = *(const bf8*)(lB + rB * 32 + (quad ^ ((col >> 1) & 3)) * 8);
    }
#pragma unroll
    for (int x = 0; x < 4; x++)
#pragma unroll
      for (int y = 0; y < 4; y++)
        acc[x][y] = MFMA(af[x], bfr[y], acc[x][y], 0, 0, 0);
  }

#pragma unroll
  for (int x = 0; x < 4; x++) {
    int s0r = m0 + wm + x * 16 + quad * 4;
#pragma unroll
    for (int y = 0; y < 4; y++) {
      f4 a = acc[x][y];
      int n = n0 + wn + y * 16 + col;
      float bv = bias[n];
#pragma unroll
      for (int r = 0; r < 4; r++) out[(size_t)(s0r + r) * DM + n] = a[r] + bv;
    }
  }
}

// =================================================================
// Split-KV flash attention with FIXED-MAX (m=0) softmax — the R4 winner.
// Grid: 16 heads x 96 chunks. qb<32: single chunk -> NORMALIZED write
// to ctx. qb>=32: 2 kv-halves -> unnormalized bf16 partial to
// slabA(=ctx)/slabB + lA/lB. 4 waves x 16 q-rows; K/V tiles in LDS.
// =================================================================
__global__ void __launch_bounds__(256, 6) attn(const unsigned short* __restrict__ Q,
                                               const unsigned short* __restrict__ K,
                                               const unsigned short* __restrict__ Vt,
                                               unsigned short* __restrict__ slabA,
                                               unsigned short* __restrict__ slabB,
                                               float* __restrict__ lA_g,
                                               float* __restrict__ lB_g) {
  __shared__ unsigned short kbuf[64 * 64];       // [kv][d], swizzled chunks
  __shared__ unsigned short vbuf[64 * 64];       // [d][kv], swizzled chunks
  __shared__ unsigned short pbuf[4 * 16 * 72];   // per-wave P[q][kv], stride 72

  int bid = blockIdx.x;
  int h = bid / 96;
  int r = 95 - (bid % 96);                       // longest chunks first
  int qb, c0, nst, isB;
  if (r < 32) { qb = r; c0 = 0; nst = r + 1; isB = 0; }
  else {
    int qq = (r - 32) >> 1;
    qb = 32 + qq;
    int half = (r - 32) & 1;
    int ntot = qb + 1, nh = (ntot + 1) >> 1;
    if (half) { c0 = nh; nst = ntot - nh; isB = 1; }
    else      { c0 = 0;  nst = nh;       isB = 0; }
  }
  bool single = (qb < 32);
  int q0blk = qb * 64;
  int t = threadIdx.x, w = t >> 6, lane = t & 63;
  int col = lane & 15, quad = lane >> 4;
  int q0 = q0blk + w * 16;

  const unsigned short* Qh = Q + (size_t)h * S * HD;
  const unsigned short* Kh = K + (size_t)h * S * HD;
  const unsigned short* Vh = Vt + (size_t)h * HD * S;
  unsigned short* pl = pbuf + w * (16 * 72);

  // Q^T B-fragments: lane holds Q[q0+col][c*32 + quad*8 + j]
  bf8 qf0 = *(const bf8*)(Qh + (q0 + col) * HD + quad * 8);
  bf8 qf1 = *(const bf8*)(Qh + (q0 + col) * HD + 32 + quad * 8);

  f4 o[4];
#pragma unroll
  for (int dt = 0; dt < 4; dt++) o[dt] = (f4){0.f, 0.f, 0.f, 0.f};
  float lsum = 0.f;                              // per-lane partial; reduced at end

  int srow = lane >> 3;          // 0..7 within an 8-row staging group
  int sphys = lane & 7;

  for (int s_ = 0; s_ < nst; s_++) {
    int kv0 = (c0 + s_) * 64;
    __syncthreads();             // WAR: prev-step k/v consumers done
#pragma unroll
    for (int p = 0; p < 2; p++) {
      int j = 2 * w + p;
      int row = j * 8 + srow;                  // 0..63
      int lch = sphys ^ (row & 7);
      gld_lds(Kh + (size_t)(kv0 + row) * HD + lch * 8, kbuf + j * 512);
      gld_lds(Vh + (size_t)row * S + kv0 + lch * 8, vbuf + j * 512);
    }
    __syncthreads();             // staged data visible

    // ---- scores S^T[kv][q] from LDS K ----
    f4 st[4];
#pragma unroll
    for (int tt = 0; tt < 4; tt++) {
      int kr = tt * 16 + col;
      int sw = col & 7;
      bf8 ka = *(const bf8*)(kbuf + kr * 64 + (quad ^ sw) * 8);
      bf8 kb = *(const bf8*)(kbuf + kr * 64 + ((quad + 4) ^ sw) * 8);
      f4 z = {0.f, 0.f, 0.f, 0.f};
      z = MFMA(ka, qf0, z, 0, 0, 0);
      z = MFMA(kb, qf1, z, 0, 0, 0);
      st[tt] = z;
    }

    if (kv0 + 63 > q0) {                       // diagonal / masked tiles
      int q = q0 + col;
#pragma unroll
      for (int tt = 0; tt < 4; tt++)
#pragma unroll
        for (int rr = 0; rr < 4; rr++) {
          int kv = kv0 + tt * 16 + quad * 4 + rr;
          st[tt][rr] = (kv <= q) ? st[tt][rr] : -1e30f;
        }
    }

    // ---- fixed-max softmax: p = exp2(st); accumulate per-lane l ----
#pragma unroll
    for (int tt = 0; tt < 4; tt++) {
      float p0 = __builtin_amdgcn_exp2f(st[tt][0]);
      float p1 = __builtin_amdgcn_exp2f(st[tt][1]);
      float p2 = __builtin_amdgcn_exp2f(st[tt][2]);
      float p3 = __builtin_amdgcn_exp2f(st[tt][3]);
      lsum += (p0 + p1) + (p2 + p3);
      s4 pk;
      pk.x = (short)f2b(p0); pk.y = (short)f2b(p1);
      pk.z = (short)f2b(p2); pk.w = (short)f2b(p3);
      // P[q=col][kv = tt*16 + quad*4 + 0..3], row stride 72 elems
      *(s4*)((char*)pl + col * 144 + tt * 32 + quad * 8) = pk;
    }

    // P A-fragments (own-wave LDS; ordering via lgkmcnt)
    bf8 pf0 = *(const bf8*)(pl + col * 72 + quad * 8);
    bf8 pf1 = *(const bf8*)(pl + col * 72 + 32 + quad * 8);

#pragma unroll
    for (int dt = 0; dt < 4; dt++) {
      int vr = dt * 16 + col;
      int sw = col & 7;
      bf8 v0 = *(const bf8*)(vbuf + vr * 64 + (quad ^ sw) * 8);
      bf8 v1 = *(const bf8*)(vbuf + vr * 64 + ((quad + 4) ^ sw) * 8);
      o[dt] = MFMA(pf0, v0, o[dt], 0, 0, 0);
      o[dt] = MFMA(pf1, v1, o[dt], 0, 0, 0);
    }
  }

  // ---- epilogue: cross-lane l reduce (q = col) ----
  lsum += __shfl_xor(lsum, 16);
  lsum += __shfl_xor(lsum, 32);

  if (single) {
    // normalize in-register, final ctx write (no combine needed)
    float inv = 1.0f / lsum;
    float ir[4];
#pragma unroll
    for (int rr = 0; rr < 4; rr++) ir[rr] = __shfl(inv, quad * 4 + rr);
#pragma unroll
    for (int dt = 0; dt < 4; dt++)
#pragma unroll
      for (int rr = 0; rr < 4; rr++) {
        int row = q0 + quad * 4 + rr;
        slabA[(size_t)row * DM + h * HD + dt * 16 + col] = f2b(o[dt][rr] * ir[rr]);
      }
  } else {
    unsigned short* slab = isB ? slabB : slabA;
    int rowbase = isB ? (q0 - 2048) : q0;        // slabB holds rows 2048+
    float* lg = isB ? lB_g : lA_g;
    if (quad == 0) lg[h * S + q0 + col] = lsum;
#pragma unroll
    for (int dt = 0; dt < 4; dt++)
#pragma unroll
      for (int rr = 0; rr < 4; rr++) {
        int row = rowbase + quad * 4 + rr;
        slab[(size_t)row * DM + h * HD + dt * 16 + col] = f2b(o[dt][rr]);
      }
  }
}

// ------------- combine bf16 partials -> normalized ctx rows 2048+ -------------
__global__ void combine(unsigned short* __restrict__ Ctx,
                        const unsigned short* __restrict__ slabB,
                        const float* __restrict__ lA_g,
                        const float* __restrict__ lB_g) {
  int row = 2048 + blockIdx.x;
  int cc = threadIdx.x * 4;
  int h = cc >> 6;
  s4 a = *(const s4*)(Ctx + (size_t)row * DM + cc);
  s4 b = *(const s4*)(slabB + (size_t)(row - 2048) * DM + cc);
  float l = lA_g[h * S + row] + lB_g[h * S + row];
  float inv = 1.0f / l;
  s4 o;
  o.x = (short)f2b((b2f((unsigned short)a.x) + b2f((unsigned short)b.x)) * inv);
  o.y = (short)f2b((b2f((unsigned short)a.y) + b2f((unsigned short)b.y)) * inv);
  o.z = (short)f2b((b2f((unsigned short)a.z) + b2f((unsigned short)b.z)) * inv);
  o.w = (short)f2b((b2f((unsigned short)a.w) + b2f((unsigned short)b.w)) * inv);
  *(s4*)(Ctx + (size_t)row * DM + cc) = o;
}

extern "C" void kernel_launch(void* const* d_in, const int* in_sizes, int n_in,
                              void* d_out, int out_size, void* d_ws, size_t ws_size,
                              hipStream_t stream) {
  const float* x     = (const float*)d_in[0];
  const float* w_qkv = (const float*)d_in[1];
  const float* b_qkv = (const float*)d_in[2];
  const float* w_out = (const float*)d_in[3];
  const float* b_out = (const float*)d_in[4];
  float* out = (float*)d_out;

  char* ws = (char*)d_ws;
  unsigned short* xb    = (unsigned short*)(ws);                        //  8 MB (dead after gemm_qkv)
  unsigned short* wqkvT = (unsigned short*)(ws + (size_t)8  * 1048576); //  6 MB (dead after gemm_qkv)
  unsigned short* woutT = (unsigned short*)(ws + (size_t)14 * 1048576); //  2 MB (live till gemm_out)
  unsigned short* Qb    = (unsigned short*)(ws + (size_t)16 * 1048576); //  8 MB
  unsigned short* Kb    = (unsigned short*)(ws + (size_t)24 * 1048576); //  8 MB
  unsigned short* Vtb   = (unsigned short*)(ws + (size_t)32 * 1048576); //  8 MB
  unsigned short* ctx   = (unsigned short*)(ws + (size_t)40 * 1048576); //  8 MB (= slabA)

  // dead-region reuse (gemm_qkv has consumed xb/wqkvT before attn runs):
  unsigned short* slabB = xb;                                           //  4 MB used (rows 2048+)
  float* lA_g = (float*)wqkvT;                                          // 256 KB
  float* lB_g = (float*)(ws + (size_t)8 * 1048576 + 512 * 1024);        // 256 KB

  prep<<<5120, 256, 0, stream>>>(x, w_qkv, w_out, xb, wqkvT, woutT);
  gemm_qkv<<<32 * 24, 256, 0, stream>>>(xb, wqkvT, b_qkv, Qb, Kb, Vtb);
  attn<<<NH * 96, 256, 0, stream>>>(Qb, Kb, Vtb, ctx, slabB, lA_g, lB_g);
  combine<<<2048, 256, 0, stream>>>(ctx, slabB, lA_g, lB_g);
  gemm_out<<<32 * 8, 256, 0, stream>>>(ctx, woutT, b_out, out);
}